// Round 2
// baseline (637.603 us; speedup 1.0000x reference)
//
#include <hip/hip_runtime.h>
#include <hip/hip_bf16.h>
#include <cstdint>

// Problem constants
#define SEQ     40
#define EMB     300
#define IMGE    384
#define XROWS   51       // LDS rows per sentence (need up to row 50 = 16*2+15+3)
#define XROWB   (XROWS * 640)   // 32640 bytes per sentence (320 bf16 cols)
#define BLOB_OFF 256

using bf16x8 = short  __attribute__((ext_vector_type(8)));
using f32x4  = float  __attribute__((ext_vector_type(4)));

__device__ __forceinline__ unsigned short f2bf(float f) {
  unsigned int u = __builtin_bit_cast(unsigned int, f);
  u += 0x7FFFu + ((u >> 16) & 1u);          // round-to-nearest-even
  return (unsigned short)(u >> 16);
}

// ---------------------------------------------------------------------------
// Prep: repack conv weights (fp32, [256][1][k][300]) into bf16 fragment-order
// blob: byte = ((kappa*768 + F)*32 + e')*2, kappa = j*10+kk, e = kk*32+e'.
// Zero-pad j >= k and e >= 300. One wave-load in the main kernel = 1KB contig.
// ---------------------------------------------------------------------------
__global__ __launch_bounds__(256) void prep_weights(
    const float* __restrict__ w2, const float* __restrict__ w3,
    const float* __restrict__ w4, unsigned short* __restrict__ blob)
{
  int kappa = blockIdx.x;                       // 0..39
  int fq = blockIdx.y * 256 + threadIdx.x;      // F*4 + q, 0..3071
  int F = fq >> 2;
  int q = fq & 3;
  int j = kappa / 10, kk = kappa - 10 * j;
  int ch = F >> 8, f = F & 255;
  int k = ch + 2;
  const float* w = (ch == 0) ? w2 : (ch == 1 ? w3 : w4);

  bf16x8 pv;
  if (j < k) {
    const float* src = w + (size_t)(f * k + j) * 300;
    #pragma unroll
    for (int i = 0; i < 8; i++) {
      int e = kk * 32 + q * 8 + i;
      pv[i] = (e < 300) ? (short)f2bf(src[e]) : (short)0;
    }
  } else {
    #pragma unroll
    for (int i = 0; i < 8; i++) pv[i] = 0;
  }
  unsigned short* dst = blob + (size_t)(kappa * 768 + F) * 32 + q * 8;
  *(bf16x8*)dst = pv;
}

// ---------------------------------------------------------------------------
// Main: one block = 1024 threads (16 waves), 2 sentences.
// Each wave owns 3 N-tiles: one 16-filter tile per channel (tile index = wv).
// Per-channel exact j-limit (ch0: j<2, ch1: j<3, ch2: j<4) -> 540 MFMA/wave,
// perfectly balanced. acc = 2s x 3m x 3n x f32x4 = 72 regs -> fits 128-VGPR
// cap -> 4 waves/SIMD resident (vs 2 before) to hide L2 B-load latency.
// ---------------------------------------------------------------------------
__global__ __launch_bounds__(1024, 4) void main_conv(
    const int*  __restrict__ sb,   const float* __restrict__ W,
    const float* __restrict__ b2,  const float* __restrict__ b3,
    const float* __restrict__ b4,  const unsigned short* __restrict__ blob,
    float* __restrict__ out, float* __restrict__ nrm)
{
  __shared__ __align__(128) char X[2 * XROWB];   // 65280 B
  const int tid = threadIdx.x;
  const int wv  = tid >> 6;                      // 0..15
  const int l   = tid & 63;
  const int l15 = l & 15;
  const int hi  = l >> 4;
  const int sp  = blockIdx.x;                    // sentence pair

  // zero LDS (covers e in [300,320) pads and rows 40..50)
  for (int off = tid * 16; off < 2 * XROWB; off += 1024 * 16)
    *(f32x4*)(X + off) = f32x4{0.f, 0.f, 0.f, 0.f};
  __syncthreads();

  // gather embeddings: 2 sentences x 40 rows x 75 float4 chunks
  for (int idx = tid; idx < 6000; idx += 1024) {
    int s   = idx / 3000;
    int rem = idx - s * 3000;
    int r   = rem / 75;
    int c4  = rem - r * 75;
    int Sid = sp * 2 + s;
    int tok = sb[Sid * 40 + r];
    float4 wvv = *(const float4*)(W + (size_t)tok * 300 + c4 * 4);
    uint2 pk;
    pk.x = (unsigned)f2bf(wvv.x) | ((unsigned)f2bf(wvv.y) << 16);
    pk.y = (unsigned)f2bf(wvv.z) | ((unsigned)f2bf(wvv.w) << 16);
    int colbyte = c4 * 8;
    int off = s * XROWB + r * 640 + (colbyte ^ ((r & 7) << 4));
    *(uint2*)(X + off) = pk;
  }
  __syncthreads();

  f32x4 acc[2][3][3];
  #pragma unroll
  for (int s = 0; s < 2; s++)
    #pragma unroll
    for (int m = 0; m < 3; m++)
      #pragma unroll
      for (int n = 0; n < 3; n++)
        acc[s][m][n] = f32x4{0.f, 0.f, 0.f, 0.f};

  // wave's B base: tile (n, wv) -> F = n*256 + wv*16; byte offset n*16384
  const char* bb = (const char*)blob + (size_t)(wv * 16 + l15) * 64 + hi * 16;

  #pragma unroll
  for (int j = 0; j < 4; j++) {
    const int nbase = (j < 2) ? 0 : (j - 1);     // first active channel
    for (int kk = 0; kk < 10; kk++) {
      int kappa = j * 10 + kk;
      bf16x8 Bf[3];
      #pragma unroll
      for (int n = nbase; n < 3; n++)
        Bf[n] = *(const bf16x8*)(bb + (size_t)kappa * 49152 + n * 16384);
      #pragma unroll
      for (int s = 0; s < 2; s++) {
        bf16x8 Af[3];
        #pragma unroll
        for (int m = 0; m < 3; m++) {
          int row = 16 * m + l15 + j;
          int colbyte = kk * 64 + hi * 16;
          int off = s * XROWB + row * 640 + (colbyte ^ ((row & 7) << 4));
          Af[m] = *(const bf16x8*)(X + off);
        }
        #pragma unroll
        for (int m = 0; m < 3; m++)
          #pragma unroll
          for (int n = nbase; n < 3; n++)
            acc[s][m][n] = __builtin_amdgcn_mfma_f32_16x16x32_bf16(
                Af[m], Bf[n], acc[s][m][n], 0, 0, 0);
      }
    }
  }

  // epilogue: maxpool(valid p) -> +bias -> relu -> norm SS + patch scatter
  float ss = 0.f;
  #pragma unroll
  for (int s = 0; s < 2; s++) {
    int Sid = sp * 2 + s;
    int b = Sid >> 9, c = Sid & 511;
    #pragma unroll
    for (int n = 0; n < 3; n++) {                // n == channel
      int F  = n * 256 + wv * 16 + l15;
      int ch = n;
      int plim = 39 - ch;                        // valid p: p < 41-k, k=ch+2
      float vmax = -1e30f;
      #pragma unroll
      for (int m = 0; m < 3; m++) {
        #pragma unroll
        for (int rg = 0; rg < 4; rg++) {
          int p = 16 * m + 4 * hi + rg;
          if (p < plim) vmax = fmaxf(vmax, acc[s][m][n][rg]);
        }
      }
      vmax = fmaxf(vmax, __shfl_xor(vmax, 16, 64));
      vmax = fmaxf(vmax, __shfl_xor(vmax, 32, 64));
      const float* bias = (ch == 0) ? b2 : (ch == 1 ? b3 : b4);
      float val = fmaxf(vmax + bias[F & 255], 0.f);
      if (hi == 0) {
        float mult = (c == 511) ? 65.f : 1.f;
        ss += mult * val * val;                  // norm uses pre-clip img
        float st = fminf(val, 1.f);              // clamp(img,-1,1), img>=0
        int fi = F & 255;
        int pi = fi >> 4, pj = fi & 15;
        if (c < 511) {
          int pr = c / 24, pc = c - pr * 24;
          out[((size_t)(b * 3 + ch) * IMGE + pr * 16 + pi) * IMGE + pc * 16 + pj] = st;
        } else {
          for (int pidx = 511; pidx < 576; pidx++) {
            int pr = pidx / 24, pc = pidx - pr * 24;
            out[((size_t)(b * 3 + ch) * IMGE + pr * 16 + pi) * IMGE + pc * 16 + pj] = st;
          }
        }
      }
    }
  }
  #pragma unroll
  for (int off = 32; off; off >>= 1) ss += __shfl_xor(ss, off, 64);
  if (l == 0) atomicAdd(nrm, ss);
}

__global__ void finalize(const float* __restrict__ nrm, float* __restrict__ out) {
  if (threadIdx.x == 0) out[3538944] = sqrtf(nrm[0]) * 0.125f;
}

extern "C" void kernel_launch(void* const* d_in, const int* in_sizes, int n_in,
                              void* d_out, int out_size, void* d_ws, size_t ws_size,
                              hipStream_t stream)
{
  const int*   sb = (const int*)d_in[0];
  const float* W  = (const float*)d_in[1];
  const float* w2 = (const float*)d_in[2];
  const float* b2 = (const float*)d_in[3];
  const float* w3 = (const float*)d_in[4];
  const float* b3 = (const float*)d_in[5];
  const float* w4 = (const float*)d_in[6];
  const float* b4 = (const float*)d_in[7];
  float* out = (float*)d_out;
  float* nrm = (float*)d_ws;
  unsigned short* blob = (unsigned short*)((char*)d_ws + BLOB_OFF);

  hipMemsetAsync(d_ws, 0, 8, stream);                       // norm accumulator
  prep_weights<<<dim3(40, 12), 256, 0, stream>>>(w2, w3, w4, blob);
  main_conv<<<2048, 1024, 0, stream>>>(sb, W, b2, b3, b4, blob, out, nrm);
  finalize<<<1, 64, 0, stream>>>(nrm, out);
}

// Round 3
// 453.955 us; speedup vs baseline: 1.4046x; 1.4046x over previous
//
#include <hip/hip_runtime.h>
#include <hip/hip_bf16.h>
#include <cstdint>

// Problem constants
#define SEQ     40
#define EMB     300
#define IMGE    384
#define XROWS   51       // LDS rows per sentence (need up to row 50 = 16*2+15+3)
#define XROWB   (XROWS * 640)   // 32640 bytes per sentence (320 bf16 cols)
#define BLOB_OFF 256

using bf16x8 = short  __attribute__((ext_vector_type(8)));
using f32x4  = float  __attribute__((ext_vector_type(4)));

__device__ __forceinline__ unsigned short f2bf(float f) {
  unsigned int u = __builtin_bit_cast(unsigned int, f);
  u += 0x7FFFu + ((u >> 16) & 1u);          // round-to-nearest-even
  return (unsigned short)(u >> 16);
}

// ---------------------------------------------------------------------------
// Prep: repack conv weights (fp32, [256][1][k][300]) into bf16 fragment-order
// blob: byte = ((kappa*768 + F)*32 + e')*2, kappa = j*10+kk, e = kk*32+e'.
// Zero-pad j >= k and e >= 300. One wave-load in the main kernel = 1KB contig.
// ---------------------------------------------------------------------------
__global__ __launch_bounds__(256) void prep_weights(
    const float* __restrict__ w2, const float* __restrict__ w3,
    const float* __restrict__ w4, unsigned short* __restrict__ blob)
{
  int kappa = blockIdx.x;                       // 0..39
  int fq = blockIdx.y * 256 + threadIdx.x;      // F*4 + q, 0..3071
  int F = fq >> 2;
  int q = fq & 3;
  int j = kappa / 10, kk = kappa - 10 * j;
  int ch = F >> 8, f = F & 255;
  int k = ch + 2;
  const float* w = (ch == 0) ? w2 : (ch == 1 ? w3 : w4);

  bf16x8 pv;
  if (j < k) {
    const float* src = w + (size_t)(f * k + j) * 300;
    #pragma unroll
    for (int i = 0; i < 8; i++) {
      int e = kk * 32 + q * 8 + i;
      pv[i] = (e < 300) ? (short)f2bf(src[e]) : (short)0;
    }
  } else {
    #pragma unroll
    for (int i = 0; i < 8; i++) pv[i] = 0;
  }
  unsigned short* dst = blob + (size_t)(kappa * 768 + F) * 32 + q * 8;
  *(bf16x8*)dst = pv;
}

// ---------------------------------------------------------------------------
// Main: one block = 512 threads (8 waves), 2 sentences (R1 structure).
// Wave tile map: 6 N-tiles = 2 per channel, F = ch*256 + (wv*2+t)*16.
//  -> exact per-channel j-limit (skip zero-padded j>=k), balanced waves:
//     1080 MFMA/wave vs 1440 uniform.
// B software-pipeline: register double-buffer one kk ahead, so each kappa's
// L2 loads are covered by the previous kappa's MFMA cluster (~350 cyc at
// 2 waves/SIMD vs ~300 cyc L2 latency).
// ---------------------------------------------------------------------------
__global__ __launch_bounds__(512, 2) void main_conv(
    const int*  __restrict__ sb,   const float* __restrict__ W,
    const float* __restrict__ b2,  const float* __restrict__ b3,
    const float* __restrict__ b4,  const unsigned short* __restrict__ blob,
    float* __restrict__ out, float* __restrict__ nrm)
{
  __shared__ __align__(128) char X[2 * XROWB];   // 65280 B
  const int tid = threadIdx.x;
  const int wv  = tid >> 6;
  const int l   = tid & 63;
  const int l15 = l & 15;
  const int hi  = l >> 4;
  const int sp  = blockIdx.x;                    // sentence pair

  // zero LDS (covers e in [300,320) pads and rows 40..50)
  for (int off = tid * 16; off < 2 * XROWB; off += 512 * 16)
    *(f32x4*)(X + off) = f32x4{0.f, 0.f, 0.f, 0.f};
  __syncthreads();

  // gather embeddings: 2 sentences x 40 rows x 75 float4 chunks
  for (int idx = tid; idx < 6000; idx += 512) {
    int s   = idx / 3000;
    int rem = idx - s * 3000;
    int r   = rem / 75;
    int c4  = rem - r * 75;
    int Sid = sp * 2 + s;
    int tok = sb[Sid * 40 + r];
    float4 wvv = *(const float4*)(W + (size_t)tok * 300 + c4 * 4);
    uint2 pk;
    pk.x = (unsigned)f2bf(wvv.x) | ((unsigned)f2bf(wvv.y) << 16);
    pk.y = (unsigned)f2bf(wvv.z) | ((unsigned)f2bf(wvv.w) << 16);
    int colbyte = c4 * 8;
    int off = s * XROWB + r * 640 + (colbyte ^ ((r & 7) << 4));
    *(uint2*)(X + off) = pk;
  }
  __syncthreads();

  f32x4 acc[2][3][6];
  #pragma unroll
  for (int s = 0; s < 2; s++)
    #pragma unroll
    for (int m = 0; m < 3; m++)
      #pragma unroll
      for (int n = 0; n < 6; n++)
        acc[s][m][n] = f32x4{0.f, 0.f, 0.f, 0.f};

  // per-lane B base; per-tile byte offset = F_base(n)*64, n -> (ch=n>>1, t=n&1)
  const char* bb = (const char*)blob + (size_t)l15 * 64 + hi * 16;
  int Foff[6];
  #pragma unroll
  for (int n = 0; n < 6; n++)
    Foff[n] = ((n >> 1) * 256 + (wv * 2 + (n & 1)) * 16) * 64;

  #pragma unroll
  for (int j = 0; j < 4; j++) {
    const int nmin = (j < 2) ? 0 : (j - 1) * 2;  // first active tile (ch >= j-1)
    bf16x8 Bf[6];
    #pragma unroll
    for (int n = 0; n < 6; n++)
      if (n >= nmin)
        Bf[n] = *(const bf16x8*)(bb + (size_t)(j * 10) * 49152 + Foff[n]);
    for (int kk = 0; kk < 10; kk++) {
      // prefetch next kappa's B (register double-buffer)
      int kapn = j * 10 + (kk < 9 ? kk + 1 : 9);
      bf16x8 Bn[6];
      #pragma unroll
      for (int n = 0; n < 6; n++)
        if (n >= nmin)
          Bn[n] = *(const bf16x8*)(bb + (size_t)kapn * 49152 + Foff[n]);
      // A fragments from LDS
      bf16x8 Af[2][3];
      int colbyte = kk * 64 + hi * 16;
      #pragma unroll
      for (int s = 0; s < 2; s++)
        #pragma unroll
        for (int m = 0; m < 3; m++) {
          int row = 16 * m + l15 + j;
          int off = s * XROWB + row * 640 + (colbyte ^ ((row & 7) << 4));
          Af[s][m] = *(const bf16x8*)(X + off);
        }
      // MFMA cluster (uses Bf loaded last iteration)
      #pragma unroll
      for (int s = 0; s < 2; s++)
        #pragma unroll
        for (int m = 0; m < 3; m++)
          #pragma unroll
          for (int n = 0; n < 6; n++)
            if (n >= nmin)
              acc[s][m][n] = __builtin_amdgcn_mfma_f32_16x16x32_bf16(
                  Af[s][m], Bf[n], acc[s][m][n], 0, 0, 0);
      // rotate
      #pragma unroll
      for (int n = 0; n < 6; n++)
        if (n >= nmin) Bf[n] = Bn[n];
    }
  }

  // epilogue: maxpool(valid p) -> +bias -> relu -> norm SS + patch scatter
  float ss = 0.f;
  #pragma unroll
  for (int s = 0; s < 2; s++) {
    int Sid = sp * 2 + s;
    int b = Sid >> 9, c = Sid & 511;
    #pragma unroll
    for (int n = 0; n < 6; n++) {
      int ch = n >> 1;
      int F  = ch * 256 + (wv * 2 + (n & 1)) * 16 + l15;
      int plim = 39 - ch;                        // valid p: p < 41-k, k=ch+2
      float vmax = -1e30f;
      #pragma unroll
      for (int m = 0; m < 3; m++) {
        #pragma unroll
        for (int rg = 0; rg < 4; rg++) {
          int p = 16 * m + 4 * hi + rg;
          if (p < plim) vmax = fmaxf(vmax, acc[s][m][n][rg]);
        }
      }
      vmax = fmaxf(vmax, __shfl_xor(vmax, 16, 64));
      vmax = fmaxf(vmax, __shfl_xor(vmax, 32, 64));
      const float* bias = (ch == 0) ? b2 : (ch == 1 ? b3 : b4);
      float val = fmaxf(vmax + bias[F & 255], 0.f);
      if (hi == 0) {
        float mult = (c == 511) ? 65.f : 1.f;
        ss += mult * val * val;                  // norm uses pre-clip img
        float st = fminf(val, 1.f);              // clamp to [0,1]; val>=0
        int fi = F & 255;
        int pi = fi >> 4, pj = fi & 15;
        if (c < 511) {
          int pr = c / 24, pc = c - pr * 24;
          out[((size_t)(b * 3 + ch) * IMGE + pr * 16 + pi) * IMGE + pc * 16 + pj] = st;
        } else {
          for (int pidx = 511; pidx < 576; pidx++) {
            int pr = pidx / 24, pc = pidx - pr * 24;
            out[((size_t)(b * 3 + ch) * IMGE + pr * 16 + pi) * IMGE + pc * 16 + pj] = st;
          }
        }
      }
    }
  }
  #pragma unroll
  for (int off = 32; off; off >>= 1) ss += __shfl_xor(ss, off, 64);
  if (l == 0) atomicAdd(nrm, ss);
}

__global__ void finalize(const float* __restrict__ nrm, float* __restrict__ out) {
  if (threadIdx.x == 0) out[3538944] = sqrtf(nrm[0]) * 0.125f;
}

extern "C" void kernel_launch(void* const* d_in, const int* in_sizes, int n_in,
                              void* d_out, int out_size, void* d_ws, size_t ws_size,
                              hipStream_t stream)
{
  const int*   sb = (const int*)d_in[0];
  const float* W  = (const float*)d_in[1];
  const float* w2 = (const float*)d_in[2];
  const float* b2 = (const float*)d_in[3];
  const float* w3 = (const float*)d_in[4];
  const float* b3 = (const float*)d_in[5];
  const float* w4 = (const float*)d_in[6];
  const float* b4 = (const float*)d_in[7];
  float* out = (float*)d_out;
  float* nrm = (float*)d_ws;
  unsigned short* blob = (unsigned short*)((char*)d_ws + BLOB_OFF);

  hipMemsetAsync(d_ws, 0, 8, stream);                       // norm accumulator
  prep_weights<<<dim3(40, 12), 256, 0, stream>>>(w2, w3, w4, blob);
  main_conv<<<2048, 512, 0, stream>>>(sb, W, b2, b3, b4, blob, out, nrm);
  finalize<<<1, 64, 0, stream>>>(nrm, out);
}